// Round 16
// baseline (289.773 us; speedup 1.0000x reference)
//
#include <hip/hip_runtime.h>
#include <hip/hip_bf16.h>
#include <math.h>

#define E_N   8192
#define K_N   16
#define HID   128
#define HEADS 8
#define HD    16
#define NRAD  64

typedef unsigned short ushort_t;
typedef __attribute__((ext_vector_type(8))) short bf16x8;
typedef __attribute__((ext_vector_type(4))) short bf16x4;
typedef __attribute__((ext_vector_type(4))) float f32x4;
typedef __attribute__((ext_vector_type(2))) float f32x2;

__device__ __forceinline__ float fast_rcp(float x){ return __builtin_amdgcn_rcpf(x); }
__device__ __forceinline__ float silu_f(float x){ return x * fast_rcp(1.f + __expf(-x)); }
__device__ __forceinline__ float sigmoid_f(float x){ return fast_rcp(1.f + __expf(-x)); }

__device__ __forceinline__ ushort_t f2b(float x){
  union { __hip_bfloat16 b; ushort_t u; } cv;
  cv.b = __float2bfloat16(x);
  return cv.u;
}
// packed f32x2 -> bf16x2 in one HW instruction (proven R6/R8/R10/R13)
__device__ __forceinline__ unsigned int pk_bf16(float a, float b){
  unsigned int r;
  asm volatile("v_cvt_pk_bf16_f32 %0, %1, %2" : "=v"(r) : "v"(a), "v"(b));
  return r;
}

// silu on a pair -> packed bf16x2 (pure C vector math — R7 lesson: no pk asm)
__device__ __forceinline__ unsigned int silu2(f32x2 x){
  f32x2 t;
  t.x = __expf(-x.x);
  t.y = __expf(-x.y);
  f32x2 d = t + 1.f;
  f32x2 r;
  r.x = fast_rcp(d.x);
  r.y = fast_rcp(d.y);
  f32x2 y = x * r;
  return pk_bf16(y.x, y.y);
}
// silu on 4 values -> bf16x4 fragment (k-order i=0..3)
__device__ __forceinline__ bf16x4 silu_pack4(f32x4 x){
  union { unsigned int u[2]; bf16x4 v; } cv;
  cv.u[0] = silu2((f32x2){x[0], x[1]});
  cv.u[1] = silu2((f32x2){x[2], x[3]});
  return cv.v;
}

// K=16 bf16 MFMA: D = A(16xK16) * B(K16x16) + C
__device__ __forceinline__ f32x4 mfma16(bf16x4 a, bf16x4 b, f32x4 c){
#if __has_builtin(__builtin_amdgcn_mfma_f32_16x16x16bf16_1k)
  return __builtin_amdgcn_mfma_f32_16x16x16bf16_1k(a, b, c, 0, 0, 0);
#else
  asm volatile("v_mfma_f32_16x16x16_bf16 %0, %1, %2, %0" : "+v"(c) : "v"(a), "v"(b));
  return c;
#endif
}

// swizzled [*][128] bf16 tile (256 B stride): byte = (row*256 + col*2) ^ ((row&7)<<4)
__device__ __forceinline__ void* lds_h(ushort_t* base, int row, int col){
  unsigned int byte = ((unsigned int)(row*256 + col*2)) ^ (((unsigned int)(row & 7)) << 4);
  return (void*)(reinterpret_cast<char*>(base) + byte);
}

// ---------------- Kernel W: pack weights (R13 layout, proven) ----------------
// W1t (16x16x32 A-layout, W1^T): K pad 97->128, row 97 = b1 (bias fold via X col97==1)
// W2t (16x16x16 A-layout, W2^T); W3t (16x16x16 A-layout, W3^T, N pad 8->16)
// Wq/Wk/Wv: canonical 16x16x32 B-layout.
__global__ __launch_bounds__(256) void wprep_kernel(
    const float* __restrict__ W1, const float* __restrict__ W2, const float* __restrict__ W3,
    const float* __restrict__ b1,
    const float* __restrict__ Wq, const float* __restrict__ Wk, const float* __restrict__ Wv,
    ushort_t* __restrict__ W1t, ushort_t* __restrict__ W2t, ushort_t* __restrict__ W3t,
    ushort_t* __restrict__ Wqf, ushort_t* __restrict__ Wkf, ushort_t* __restrict__ Wvf)
{
  int idx = blockIdx.x*256 + threadIdx.x;    // 0..83967
  if (idx < 16384){
    int i  = idx & 7;
    int l  = (idx >> 3) & 63;
    int ks = (idx >> 9) & 3;
    int ff = (idx >> 11) & 7;
    int kk = ks*32 + (l>>4)*8 + i;
    int f  = ff*16 + (l&15);
    float val = (kk < 97) ? W1[kk*128 + f] : (kk == 97 ? b1[f] : 0.f);
    W1t[idx] = f2b(val);
  } else if (idx < 32768){
    int id = idx - 16384;
    int i  = id & 3;
    int l  = (id >> 2) & 63;
    int ks = (id >> 8) & 7;
    int gf = (id >> 11) & 7;
    int f  = ks*16 + (l>>4)*4 + i;
    int g  = gf*16 + (l&15);
    W2t[id] = f2b(W2[f*128 + g]);
  } else if (idx < 34816){
    int id = idx - 32768;                    // 0..2047
    int i  = id & 3;
    int l  = (id >> 2) & 63;
    int ks = (id >> 8) & 7;
    int g  = ks*16 + (l>>4)*4 + i;
    int n  = l & 15;
    W3t[id] = (n < 8) ? f2b(W3[g*8 + n]) : (ushort_t)0;
  } else if (idx < 83968){
    int id = idx - 34816;                    // 0..49151
    int m  = id >> 14;                       // 0:q 1:k 2:v
    int r  = id & 16383;
    int i  = r & 7;
    int l  = (r >> 3) & 63;
    int nf = (r >> 9) & 7;
    int ks = (r >> 12) & 3;
    int kk = ks*32 + (l>>4)*8 + i;
    int n  = nf*16 + (l&15);
    const float* Wm = (m==0) ? Wq : ((m==1) ? Wk : Wv);
    ushort_t*    Dm = (m==0) ? Wqf : ((m==1) ? Wkf : Wvf);
    Dm[r] = f2b(Wm[kk*128 + n]);
  }
}

// ---------------- Kernel A: q,k,v = ef @ {Wq,Wk,Wv} via bf16 MFMA (R10 proven) ------
__global__ __launch_bounds__(256) void qkv_mfma(
    const float* __restrict__ ef,
    const ushort_t* __restrict__ Wqf, const ushort_t* __restrict__ Wkf,
    const ushort_t* __restrict__ Wvf,
    float* __restrict__ q, float* __restrict__ k, float* __restrict__ v)
{
  __shared__ __align__(16) ushort_t EfT[64*128];   // swizzled bf16 tile (256 B stride)
  const int t = threadIdx.x;
  const int w  = t >> 6;
  const int l  = t & 63;
  const int lr = l & 15;
  const int lg = l >> 4;
  const int base = blockIdx.x * 64;

  {
    int r = t >> 2, qr = t & 3;
    const float4* src = reinterpret_cast<const float4*>(ef + (base + r)*128 + qr*32);
    #pragma unroll
    for (int i4=0;i4<8;i4++){
      float4 xv = src[i4];
      *reinterpret_cast<unsigned int*>(lds_h(EfT, r, qr*32 + i4*4    )) = pk_bf16(xv.x, xv.y);
      *reinterpret_cast<unsigned int*>(lds_h(EfT, r, qr*32 + i4*4 + 2)) = pk_bf16(xv.z, xv.w);
    }
  }
  __syncthreads();

  bf16x8 Afr[4][4];
  #pragma unroll
  for (int mf=0;mf<4;mf++)
    #pragma unroll
    for (int ks=0;ks<4;ks++)
      Afr[mf][ks] = *reinterpret_cast<const bf16x8*>(lds_h(EfT, mf*16 + lr, ks*32 + lg*8));

  #pragma unroll
  for (int m=0;m<3;m++){
    const ushort_t* Wf = (m==0) ? Wqf : ((m==1) ? Wkf : Wvf);
    float*          Om = (m==0) ? q   : ((m==1) ? k   : v);
    f32x4 acc[4][2];
    #pragma unroll
    for (int mf=0;mf<4;mf++){ acc[mf][0] = (f32x4)0.f; acc[mf][1] = (f32x4)0.f; }
    #pragma unroll
    for (int ks=0; ks<4; ks++){
      bf16x8 B0 = *reinterpret_cast<const bf16x8*>(Wf + ((ks*8 + w*2+0)*64 + l)*8);
      bf16x8 B1 = *reinterpret_cast<const bf16x8*>(Wf + ((ks*8 + w*2+1)*64 + l)*8);
      #pragma unroll
      for (int mf=0; mf<4; mf++){
        acc[mf][0] = __builtin_amdgcn_mfma_f32_16x16x32_bf16(Afr[mf][ks], B0, acc[mf][0], 0,0,0);
        acc[mf][1] = __builtin_amdgcn_mfma_f32_16x16x32_bf16(Afr[mf][ks], B1, acc[mf][1], 0,0,0);
      }
    }
    #pragma unroll
    for (int mf=0;mf<4;mf++)
      #pragma unroll
      for (int nf=0;nf<2;nf++)
        #pragma unroll
        for (int i=0;i<4;i++){
          int row = base + mf*16 + lg*4 + i;
          int col = w*32 + nf*16 + lr;
          Om[row*128 + col] = acc[mf][nf][i];
        }
  }
}

// ---------------- Kernel B: gate[e][h] ----------------
__global__ __launch_bounds__(256) void gate_kernel(
    const float* __restrict__ v,
    const float* __restrict__ Wg1, const float* __restrict__ bg1,
    const float* __restrict__ Wg2, const float* __restrict__ bg2,
    float* __restrict__ gate)
{
  const int e = blockIdx.x;
  const int t = threadIdx.x;
  const int h = t >> 5, l = t & 31;
  float vp[16];
  #pragma unroll
  for (int i=0;i<16;i++) vp[i] = v[e*128 + h*16 + i];
  float part = 0.f;
  #pragma unroll
  for (int jj=0;jj<4;jj++){
    int j = l + jj*32;
    float a = bg1[j];
    #pragma unroll
    for (int i=0;i<16;i++) a += vp[i]*Wg1[i*128+j];
    part += silu_f(a) * Wg2[j];
  }
  #pragma unroll
  for (int off=16; off>=1; off>>=1) part += __shfl_xor(part, off, 64);
  if (l==0) gate[e*8+h] = sigmoid_f(part + bg2[0]);
}

// ---------------- Kernel C: MFMA fused edge attention (8-wave register MLP) --------
// 512 threads.  Setup (X build): R13 code VERBATIM under wave-uniform `if (t<256)`
// (waves 0-3 build all 128 rows; proven).  All 8 waves then run the barrier-free
// register-resident MLP on rows [16w, 16w+16) (1 r-frag each, full K=128 GEMM1 with
// dot/b1 folded into X cols 96/97 as in R13).  Epilogue: R13 verbatim under t<256
// guards with hoisted barriers (R12-proven pattern).  LDS 35 KB -> 4 blocks x 8
// waves = 32 waves/CU cap.
__global__ __launch_bounds__(512) void edge_attn_mfma(
    const float* __restrict__ ef, const float* __restrict__ coords,
    const float* __restrict__ q, const float* __restrict__ k, const float* __restrict__ v,
    const ushort_t* __restrict__ W1t, const ushort_t* __restrict__ W2t,
    const ushort_t* __restrict__ W3t,
    const float* __restrict__ b2, const float* __restrict__ b3,
    const float* __restrict__ Wo, const float* __restrict__ bo,
    const float* __restrict__ gamma, const float* __restrict__ beta,
    const int* __restrict__ pairs, const float* __restrict__ gate,
    float* __restrict__ out_y, float* __restrict__ out_c)
{
  __shared__ __align__(16) ushort_t BufA[128*128];   // X (swizzled, 256 B stride)
  __shared__ __align__(16) float SmallBuf[416];      // sc[128], attn[128], feats[128], red[4]
  __shared__ float cd_l[16][4];
  __shared__ float gate_l[16][8];
  __shared__ int   dstl[16];

  float* sc_l   = SmallBuf;          // reused as wopart[256] in epilogue
  float* attn_l = SmallBuf + 128;
  float* feats  = SmallBuf + 256;
  float* red    = SmallBuf + 384;
  float* wopart = SmallBuf;

  const int e = blockIdx.x;
  const int t = threadIdx.x;
  const int w  = t >> 6;        // 0..7
  const int l  = t & 63;
  const int lr = l & 15;
  const int lg = l >> 4;

  // ---------- setup (R13 verbatim), waves 0-3 only (wave-uniform guard) ----------
  if (t < 256){
    const int pg   = lg;               // 0..3, lane-group's pair within the wave
    const int p    = w*4 + pg;
    const int dstp = pairs[(e*16 + p)*2 + 1];
    if (l < 4) dstl[w*4 + l] = pairs[(e*16 + w*4 + l)*2 + 1];

    float cx = coords[e*3+0]-coords[dstp*3+0];
    float cy = coords[e*3+1]-coords[dstp*3+1];
    float cz = coords[e*3+2]-coords[dstp*3+2];
    float dist = sqrtf(cx*cx+cy*cy+cz*cz);
    if (lr < 3) cd_l[p][lr] = (lr==0) ? cx : (lr==1 ? cy : cz);

    // rb: each lane computes 4 centers, writes packed to all 8 rows of its pair
    {
      int i0 = lr * 4;
      float z0 = (dist - (float)(i0+0)*(10.0f/63.0f)) * 6.4f;
      float z1 = (dist - (float)(i0+1)*(10.0f/63.0f)) * 6.4f;
      float z2 = (dist - (float)(i0+2)*(10.0f/63.0f)) * 6.4f;
      float z3 = (dist - (float)(i0+3)*(10.0f/63.0f)) * 6.4f;
      unsigned int u01 = pk_bf16(__expf(-z0*z0), __expf(-z1*z1));
      unsigned int u23 = pk_bf16(__expf(-z2*z2), __expf(-z3*z3));
      int base_row = w*32 + pg*8;
      #pragma unroll
      for (int rr=0; rr<8; rr++){
        *reinterpret_cast<unsigned int*>(lds_h(BufA, base_row+rr, 32+i0  )) = u01;
        *reinterpret_cast<unsigned int*>(lds_h(BufA, base_row+rr, 32+i0+2)) = u23;
      }
    }

    // q/k/dot/bias-1/zeros: 2 lanes per row (rows [32w, 32w+32))
    {
      const int rl  = l >> 1;
      const int hf  = l & 1;
      const int row = w*32 + rl;
      const int hh  = rl & 7;
      float dot = 0.f;
      if (hf == 0){
        const float4* qp4 = reinterpret_cast<const float4*>(q + e*128 + hh*16);
        const float4* kp4 = reinterpret_cast<const float4*>(k + dstp*128 + hh*16);
        #pragma unroll
        for (int i4=0;i4<4;i4++){
          float4 qv = qp4[i4], kv = kp4[i4];
          dot += qv.x*kv.x + qv.y*kv.y + qv.z*kv.z + qv.w*kv.w;
          *reinterpret_cast<unsigned int*>(lds_h(BufA, row, i4*4     )) = pk_bf16(qv.x, qv.y);
          *reinterpret_cast<unsigned int*>(lds_h(BufA, row, i4*4+2   )) = pk_bf16(qv.z, qv.w);
          *reinterpret_cast<unsigned int*>(lds_h(BufA, row, 16+i4*4  )) = pk_bf16(kv.x, kv.y);
          *reinterpret_cast<unsigned int*>(lds_h(BufA, row, 16+i4*4+2)) = pk_bf16(kv.z, kv.w);
        }
      }
      float dsw = __shfl_xor(dot, 1, 64);
      if (hf == 1){
        *reinterpret_cast<unsigned int*>(lds_h(BufA, row, 96)) = pk_bf16(dsw, 1.0f);
        #pragma unroll
        for (int c=98;c<128;c+=2)
          *reinterpret_cast<unsigned int*>(lds_h(BufA, row, c)) = 0u;
      }
    }
  }
  __syncthreads();     // X complete (all 8 waves)

  // ---------- register-resident MLP: wave w owns rows [16w, 16w+16) ----------
  bf16x8 Xb[4];
  #pragma unroll
  for (int ks=0; ks<4; ks++)
    Xb[ks] = *reinterpret_cast<const bf16x8*>(lds_h(BufA, w*16 + lr, ks*32 + lg*8));

  // GEMM1 (full K=128; dot/b1 folded via X cols 96/97)
  bf16x4 B1s[8];
  #pragma unroll
  for (int ff=0; ff<8; ff++){
    f32x4 a0 = (f32x4)0.f;
    #pragma unroll
    for (int ks=0; ks<4; ks++){
      bf16x8 A = *reinterpret_cast<const bf16x8*>(W1t + (ff*2048 + ks*512 + l*8));
      a0 = __builtin_amdgcn_mfma_f32_16x16x32_bf16(A, Xb[ks], a0, 0,0,0);
    }
    B1s[ff] = silu_pack4(a0);
  }

  // GEMM2 + GEMM3 fused (per g-fragment)
  f32x4 s0 = (f32x4)0.f;
  #pragma unroll
  for (int gf=0; gf<8; gf++){
    f32x4 c0 = (f32x4)0.f;
    #pragma unroll
    for (int ks=0; ks<8; ks++){
      bf16x4 A2 = *reinterpret_cast<const bf16x4*>(W2t + (gf*2048 + ks*256 + l*4));
      c0 = mfma16(A2, B1s[ks], c0);
    }
    f32x4 b2v = *reinterpret_cast<const f32x4*>(b2 + gf*16 + lg*4);
    c0 += b2v;
    bf16x4 h0 = silu_pack4(c0);
    bf16x4 A3 = *reinterpret_cast<const bf16x4*>(W3t + (gf*256 + l*4));
    s0 = mfma16(A3, h0, s0);
  }

  // score write: batch row r = w*16+lr needs head n = l&7, held by group (l&7)>>2
  if (lg == ((l & 7) >> 2)){
    sc_l[w*16 + lr] = s0[l & 3] + b3[l & 7];
  }
  __syncthreads();

  // ---------- softmax over 16 pairs per head (rows p*8+h) ----------
  if (t < 8){
    const int h = t;
    float m = -1e30f;
    for (int pp=0;pp<16;pp++) m = fmaxf(m, sc_l[pp*8+h]);
    float den = 0.f;
    for (int pp=0;pp<16;pp++){ float wgt = __expf(sc_l[pp*8+h]-m); attn_l[pp*8+h]=wgt; den += wgt; }
    float inv = fast_rcp(den);
    for (int pp=0;pp<16;pp++) attn_l[pp*8+h] *= inv;
  }
  if (t >= 128 && t < 256){
    int idx = t - 128; int pp = idx>>3, h = idx&7;
    gate_l[pp][h] = gate[dstl[pp]*8 + h];
  }
  __syncthreads();

  // ---------- aggregation ----------
  if (t < 128){
    const int h = t >> 4;
    float s = 0.f;
    #pragma unroll
    for (int pp=0;pp<16;pp++) s += attn_l[pp*8+h] * v[dstl[pp]*128 + t];
    feats[t] = s;
  }
  if (t >= 128 && t < 144){
    int pp = t-128;
    float s = 0.f;
    #pragma unroll
    for (int h=0;h<8;h++) s += attn_l[pp*8+h]*gate_l[pp][h];
    cd_l[pp][3] = s;
  }
  __syncthreads();
  if (t < 3){
    float s = 0.f;
    #pragma unroll
    for (int pp=0;pp<16;pp++) s += cd_l[pp][3]*cd_l[pp][t];
    out_c[e*3+t] = coords[e*3+t] + s*0.125f;
  }

  // ---------- y = ef + feats@Wo + bo (2-half K split, waves 0-3; R12-proven) -------
  f32x2 a2 = {0.f, 0.f};
  if (t < 256){
    const int col  = t & 127;
    const int half = t >> 7;
    const float* feats2 = feats + half*64;
    const float* Wocol  = Wo + half*64*128 + col;
    #pragma unroll
    for (int iq=0; iq<32; iq++){
      f32x2 x2 = *reinterpret_cast<const f32x2*>(feats2 + iq*2);
      f32x2 w2 = { Wocol[(iq*2)*128], Wocol[(iq*2+1)*128] };
      a2 += x2 * w2;
    }
  }
  __syncthreads();               // attn_l/sc_l reads all done; safe to overwrite
  if (t < 256) wopart[t] = a2.x + a2.y;
  __syncthreads();

  float yv = 0.f;
  if (t < 128){
    yv = ef[e*128+t] + wopart[t] + wopart[t+128] + bo[t];
    float s1v = yv, s2v = yv*yv;
    #pragma unroll
    for (int off=32; off>=1; off>>=1){ s1v += __shfl_xor(s1v,off,64); s2v += __shfl_xor(s2v,off,64); }
    if ((t&63)==0){ red[(t>>6)*2+0]=s1v; red[(t>>6)*2+1]=s2v; }
  }
  __syncthreads();
  if (t < 128){
    float sm = red[0]+red[2], sq = red[1]+red[3];
    float mean = sm * (1.f/128.f);
    float var  = sq * (1.f/128.f) - mean*mean;
    float rstd = rsqrtf(var + 1e-5f);
    out_y[e*128+t] = (yv-mean)*rstd*gamma[t] + beta[t];
  }
}

extern "C" void kernel_launch(void* const* d_in, const int* in_sizes, int n_in,
                              void* d_out, int out_size, void* d_ws, size_t ws_size,
                              hipStream_t stream)
{
  const float* ef     = (const float*)d_in[0];
  const float* coords = (const float*)d_in[1];
  const float* Wq  = (const float*)d_in[2];
  const float* Wk  = (const float*)d_in[3];
  const float* Wv  = (const float*)d_in[4];
  const float* W1  = (const float*)d_in[5];
  const float* b1  = (const float*)d_in[6];
  const float* W2  = (const float*)d_in[7];
  const float* b2  = (const float*)d_in[8];
  const float* W3  = (const float*)d_in[9];
  const float* b3  = (const float*)d_in[10];
  const float* Wg1 = (const float*)d_in[11];
  const float* bg1 = (const float*)d_in[12];
  const float* Wg2 = (const float*)d_in[13];
  const float* bg2 = (const float*)d_in[14];
  const float* Wo  = (const float*)d_in[15];
  const float* bo  = (const float*)d_in[16];
  const float* gamma = (const float*)d_in[17];
  const float* beta  = (const float*)d_in[18];
  const int*   pairs = (const int*)d_in[19];

  float* ws   = (float*)d_ws;
  float* q    = ws;
  float* k    = q + E_N*HID;
  float* v    = k + E_N*HID;
  float* gate = v + E_N*HID;
  ushort_t* W1t = (ushort_t*)(gate + E_N*HEADS);
  ushort_t* W2t = W1t + 16384;
  ushort_t* W3t = W2t + 16384;
  ushort_t* Wqf = W3t + 2048;
  ushort_t* Wkf = Wqf + 16384;
  ushort_t* Wvf = Wkf + 16384;

  wprep_kernel<<<328, 256, 0, stream>>>(W1, W2, W3, b1, Wq, Wk, Wv,
      W1t, W2t, W3t, Wqf, Wkf, Wvf);
  qkv_mfma<<<E_N/64, 256, 0, stream>>>(ef, Wqf, Wkf, Wvf, q, k, v);
  gate_kernel<<<E_N, 256, 0, stream>>>(v, Wg1, bg1, Wg2, bg2, gate);
  edge_attn_mfma<<<E_N, 512, 0, stream>>>(ef, coords, q, k, v,
      W1t, W2t, W3t, b2, b3, Wo, bo, gamma, beta, pairs, gate,
      (float*)d_out, (float*)d_out + E_N*HID);
}

// Round 17
// 195.467 us; speedup vs baseline: 1.4825x; 1.4825x over previous
//
#include <hip/hip_runtime.h>
#include <hip/hip_bf16.h>
#include <math.h>

#define E_N   8192
#define K_N   16
#define HID   128
#define HEADS 8
#define HD    16
#define NRAD  64

typedef unsigned short ushort_t;
typedef __attribute__((ext_vector_type(8))) short bf16x8;
typedef __attribute__((ext_vector_type(4))) float f32x4;
typedef __attribute__((ext_vector_type(2))) float f32x2;

__device__ __forceinline__ float fast_rcp(float x){ return __builtin_amdgcn_rcpf(x); }
__device__ __forceinline__ float silu_f(float x){ return x * fast_rcp(1.f + __expf(-x)); }
__device__ __forceinline__ float sigmoid_f(float x){ return fast_rcp(1.f + __expf(-x)); }

__device__ __forceinline__ ushort_t f2b(float x){
  union { __hip_bfloat16 b; ushort_t u; } cv;
  cv.b = __float2bfloat16(x);
  return cv.u;
}
// packed f32x2 -> bf16x2 in one HW instruction (proven R6/R8/R10)
__device__ __forceinline__ unsigned int pk_bf16(float a, float b){
  unsigned int r;
  asm volatile("v_cvt_pk_bf16_f32 %0, %1, %2" : "=v"(r) : "v"(a), "v"(b));
  return r;
}

// silu on a pair -> packed bf16x2 (pure C vector math — R7 lesson: no pk asm)
__device__ __forceinline__ unsigned int silu2(f32x2 x){
  f32x2 t;
  t.x = __expf(-x.x);
  t.y = __expf(-x.y);
  f32x2 d = t + 1.f;
  f32x2 r;
  r.x = fast_rcp(d.x);
  r.y = fast_rcp(d.y);
  f32x2 y = x * r;
  return pk_bf16(y.x, y.y);
}

// swizzled [*][128] bf16 tile: byte = (row*256 + col*2) ^ ((row&7)<<4)
__device__ __forceinline__ void* lds_h(ushort_t* base, int row, int col){
  unsigned int byte = ((unsigned int)(row*256 + col*2)) ^ (((unsigned int)(row & 7)) << 4);
  return (void*)(reinterpret_cast<char*>(base) + byte);
}

// ---------------- Kernel W: pack W1/W2/W3 + Wq/Wk/Wv into MFMA B-frag bf16 --------
// Paired layout (W1,W2): n = (nf>>1)*32 + 2*(l&15) + (nf&1)
// Canonical layout (W3, Wq/Wk/Wv): n = nf*16 + (l&15)
// k = ks*32 + (l>>4)*8 + i for all.  W1: K pad 97->128 with row97 = b1.  W3: N pad 8->16.
__global__ __launch_bounds__(256) void wprep_kernel(
    const float* __restrict__ W1, const float* __restrict__ W2, const float* __restrict__ W3,
    const float* __restrict__ b1,
    const float* __restrict__ Wq, const float* __restrict__ Wk, const float* __restrict__ Wv,
    ushort_t* __restrict__ W1f, ushort_t* __restrict__ W2f, ushort_t* __restrict__ W3f,
    ushort_t* __restrict__ Wqf, ushort_t* __restrict__ Wkf, ushort_t* __restrict__ Wvf)
{
  int idx = blockIdx.x*256 + threadIdx.x;    // 0..83967
  if (idx < 32768){
    int id  = idx & 16383;
    int i  = id & 7;
    int l  = (id >> 3) & 63;
    int nf = (id >> 9) & 7;
    int ks = (id >> 12) & 3;
    int kk = ks*32 + (l>>4)*8 + i;
    int n  = (nf>>1)*32 + 2*(l&15) + (nf&1);
    if (idx < 16384){
      float val = (kk < 97) ? W1[kk*128 + n] : (kk == 97 ? b1[n] : 0.f);
      W1f[id] = f2b(val);
    } else {
      W2f[id] = f2b(W2[kk*128 + n]);
    }
  } else if (idx < 34816){
    int id = idx - 32768;                    // 0..2047
    int i  = id & 7;
    int l  = (id >> 3) & 63;
    int ks = (id >> 9) & 3;
    int kk = ks*32 + (l>>4)*8 + i;
    int n  = l & 15;
    W3f[id] = (n < 8) ? f2b(W3[kk*8 + n]) : (ushort_t)0;
  } else if (idx < 83968){
    int id = idx - 34816;                    // 0..49151
    int m  = id >> 14;                       // 0:q 1:k 2:v
    int r  = id & 16383;
    int i  = r & 7;
    int l  = (r >> 3) & 63;
    int nf = (r >> 9) & 7;
    int ks = (r >> 12) & 3;
    int kk = ks*32 + (l>>4)*8 + i;
    int n  = nf*16 + (l&15);
    const float* Wm = (m==0) ? Wq : ((m==1) ? Wk : Wv);
    ushort_t*    Dm = (m==0) ? Wqf : ((m==1) ? Wkf : Wvf);
    Dm[r] = f2b(Wm[kk*128 + n]);
  }
}

// ---------------- Kernel A: q,k,v = ef @ {Wq,Wk,Wv} via bf16 MFMA ----------------
__global__ __launch_bounds__(256) void qkv_mfma(
    const float* __restrict__ ef,
    const ushort_t* __restrict__ Wqf, const ushort_t* __restrict__ Wkf,
    const ushort_t* __restrict__ Wvf,
    float* __restrict__ q, float* __restrict__ k, float* __restrict__ v)
{
  __shared__ __align__(16) ushort_t EfT[64*128];   // swizzled bf16 tile
  const int t = threadIdx.x;
  const int w  = t >> 6;
  const int l  = t & 63;
  const int lr = l & 15;
  const int lg = l >> 4;
  const int base = blockIdx.x * 64;

  {
    int r = t >> 2, qr = t & 3;
    const float4* src = reinterpret_cast<const float4*>(ef + (base + r)*128 + qr*32);
    #pragma unroll
    for (int i4=0;i4<8;i4++){
      float4 xv = src[i4];
      *reinterpret_cast<unsigned int*>(lds_h(EfT, r, qr*32 + i4*4    )) = pk_bf16(xv.x, xv.y);
      *reinterpret_cast<unsigned int*>(lds_h(EfT, r, qr*32 + i4*4 + 2)) = pk_bf16(xv.z, xv.w);
    }
  }
  __syncthreads();

  bf16x8 Afr[4][4];
  #pragma unroll
  for (int mf=0;mf<4;mf++)
    #pragma unroll
    for (int ks=0;ks<4;ks++)
      Afr[mf][ks] = *reinterpret_cast<const bf16x8*>(lds_h(EfT, mf*16 + lr, ks*32 + lg*8));

  #pragma unroll
  for (int m=0;m<3;m++){
    const ushort_t* Wf = (m==0) ? Wqf : ((m==1) ? Wkf : Wvf);
    float*          Om = (m==0) ? q   : ((m==1) ? k   : v);
    f32x4 acc[4][2];
    #pragma unroll
    for (int mf=0;mf<4;mf++){ acc[mf][0] = (f32x4)0.f; acc[mf][1] = (f32x4)0.f; }
    #pragma unroll
    for (int ks=0; ks<4; ks++){
      bf16x8 B0 = *reinterpret_cast<const bf16x8*>(Wf + ((ks*8 + w*2+0)*64 + l)*8);
      bf16x8 B1 = *reinterpret_cast<const bf16x8*>(Wf + ((ks*8 + w*2+1)*64 + l)*8);
      #pragma unroll
      for (int mf=0; mf<4; mf++){
        acc[mf][0] = __builtin_amdgcn_mfma_f32_16x16x32_bf16(Afr[mf][ks], B0, acc[mf][0], 0,0,0);
        acc[mf][1] = __builtin_amdgcn_mfma_f32_16x16x32_bf16(Afr[mf][ks], B1, acc[mf][1], 0,0,0);
      }
    }
    #pragma unroll
    for (int mf=0;mf<4;mf++)
      #pragma unroll
      for (int nf=0;nf<2;nf++)
        #pragma unroll
        for (int i=0;i<4;i++){
          int row = base + mf*16 + lg*4 + i;
          int col = w*32 + nf*16 + lr;
          Om[row*128 + col] = acc[mf][nf][i];
        }
  }
}

// ---------------- Kernel B: gate[e][h] ----------------
__global__ __launch_bounds__(256) void gate_kernel(
    const float* __restrict__ v,
    const float* __restrict__ Wg1, const float* __restrict__ bg1,
    const float* __restrict__ Wg2, const float* __restrict__ bg2,
    float* __restrict__ gate)
{
  const int e = blockIdx.x;
  const int t = threadIdx.x;
  const int h = t >> 5, l = t & 31;
  float vp[16];
  #pragma unroll
  for (int i=0;i<16;i++) vp[i] = v[e*128 + h*16 + i];
  float part = 0.f;
  #pragma unroll
  for (int jj=0;jj<4;jj++){
    int j = l + jj*32;
    float a = bg1[j];
    #pragma unroll
    for (int i=0;i<16;i++) a += vp[i]*Wg1[i*128+j];
    part += silu_f(a) * Wg2[j];
  }
  #pragma unroll
  for (int off=16; off>=1; off>>=1) part += __shfl_xor(part, off, 64);
  if (l==0) gate[e*8+h] = sigmoid_f(part + bg2[0]);
}

// ---------------- Kernel C: MFMA fused edge attention (R8/R10 structure) -----------
// N-split: wave w owns output cols [32w, 32w+32).  Two M-passes per layer with
// acc[4][2] (32 AGPR).  X/H1/H2 time-share ONE 32 KB swizzled LDS tile.
__global__ __launch_bounds__(256) void edge_attn_mfma(
    const float* __restrict__ ef, const float* __restrict__ coords,
    const float* __restrict__ q, const float* __restrict__ k, const float* __restrict__ v,
    const ushort_t* __restrict__ W1f, const ushort_t* __restrict__ W2f,
    const ushort_t* __restrict__ W3f,
    const float* __restrict__ b2, const float* __restrict__ b3,
    const float* __restrict__ Wo, const float* __restrict__ bo,
    const float* __restrict__ gamma, const float* __restrict__ beta,
    const int* __restrict__ pairs, const float* __restrict__ gate,
    float* __restrict__ out_y, float* __restrict__ out_c)
{
  __shared__ __align__(16) ushort_t BufA[128*128];   // X -> H1 -> H2 (swizzled)
  __shared__ __align__(16) float SmallBuf[416];      // sc[128], attn[128], feats[128], red[4]
  __shared__ float cd_l[16][4];
  __shared__ float gate_l[16][8];
  __shared__ int   dstl[16];

  float* sc_l   = SmallBuf;          // reused as wopart[256] in epilogue
  float* attn_l = SmallBuf + 128;
  float* feats  = SmallBuf + 256;
  float* red    = SmallBuf + 384;
  float* wopart = SmallBuf;

  const int e = blockIdx.x;
  const int t = threadIdx.x;
  const int w  = t >> 6;
  const int l  = t & 63;
  const int lr = l & 15;        // A-row / B-col / C-col within fragment
  const int lg = l >> 4;        // k-group / C-row-group (= pair group in setup)

  // ---------- per-lane setup: pair, coord diff, rb (all wave-local) ----------
  const int pg   = lg;                 // 0..3, this lane-group's pair within the wave
  const int p    = w*4 + pg;
  const int dstp = pairs[(e*16 + p)*2 + 1];
  if (l < 4) dstl[w*4 + l] = pairs[(e*16 + w*4 + l)*2 + 1];

  float cx = coords[e*3+0]-coords[dstp*3+0];
  float cy = coords[e*3+1]-coords[dstp*3+1];
  float cz = coords[e*3+2]-coords[dstp*3+2];
  float dist = sqrtf(cx*cx+cy*cy+cz*cz);
  if (lr < 3) cd_l[p][lr] = (lr==0) ? cx : (lr==1 ? cy : cz);

  // rb: each lane computes 4 centers, writes them (packed) to all 8 rows of its pair
  {
    int i0 = lr * 4;
    float z0 = (dist - (float)(i0+0)*(10.0f/63.0f)) * 6.4f;
    float z1 = (dist - (float)(i0+1)*(10.0f/63.0f)) * 6.4f;
    float z2 = (dist - (float)(i0+2)*(10.0f/63.0f)) * 6.4f;
    float z3 = (dist - (float)(i0+3)*(10.0f/63.0f)) * 6.4f;
    unsigned int u01 = pk_bf16(__expf(-z0*z0), __expf(-z1*z1));
    unsigned int u23 = pk_bf16(__expf(-z2*z2), __expf(-z3*z3));
    int base_row = w*32 + pg*8;
    #pragma unroll
    for (int rr=0; rr<8; rr++){
      *reinterpret_cast<unsigned int*>(lds_h(BufA, base_row+rr, 32+i0  )) = u01;
      *reinterpret_cast<unsigned int*>(lds_h(BufA, base_row+rr, 32+i0+2)) = u23;
    }
  }

  // q/k/dot/bias-1/zeros: 2 lanes per row (wave-local rows [32w, 32w+32))
  {
    const int rl  = l >> 1;
    const int hf  = l & 1;
    const int row = w*32 + rl;
    const int hh  = rl & 7;
    float dot = 0.f;
    if (hf == 0){
      const float4* qp4 = reinterpret_cast<const float4*>(q + e*128 + hh*16);
      const float4* kp4 = reinterpret_cast<const float4*>(k + dstp*128 + hh*16);
      #pragma unroll
      for (int i4=0;i4<4;i4++){
        float4 qv = qp4[i4], kv = kp4[i4];
        dot += qv.x*kv.x + qv.y*kv.y + qv.z*kv.z + qv.w*kv.w;
        *reinterpret_cast<unsigned int*>(lds_h(BufA, row, i4*4     )) = pk_bf16(qv.x, qv.y);
        *reinterpret_cast<unsigned int*>(lds_h(BufA, row, i4*4+2   )) = pk_bf16(qv.z, qv.w);
        *reinterpret_cast<unsigned int*>(lds_h(BufA, row, 16+i4*4  )) = pk_bf16(kv.x, kv.y);
        *reinterpret_cast<unsigned int*>(lds_h(BufA, row, 16+i4*4+2)) = pk_bf16(kv.z, kv.w);
      }
    }
    float dsw = __shfl_xor(dot, 1, 64);
    if (hf == 1){
      *reinterpret_cast<unsigned int*>(lds_h(BufA, row, 96)) = pk_bf16(dsw, 1.0f);
      #pragma unroll
      for (int c=98;c<128;c+=2)
        *reinterpret_cast<unsigned int*>(lds_h(BufA, row, c)) = 0u;
    }
  }
  __syncthreads();     // X complete

  const int c0 = w*32 + 2*lr;               // this wave's packed output col pair
  const f32x2 b2p = { b2[c0], b2[c0+1] };   // layer-2 bias (layer-1 bias folded)

  // ===== layer 1: two M-passes, acc[4][2] =====
  #pragma unroll
  for (int pass=0; pass<2; ++pass){
    f32x4 acc[4][2];
    #pragma unroll
    for (int mf=0;mf<4;mf++){ acc[mf][0] = (f32x4)0.f; acc[mf][1] = (f32x4)0.f; }
    #pragma unroll
    for (int ks=0; ks<4; ks++){
      bf16x8 B0 = *reinterpret_cast<const bf16x8*>(W1f + ((ks*8 + w*2+0)*64 + l)*8);
      bf16x8 B1 = *reinterpret_cast<const bf16x8*>(W1f + ((ks*8 + w*2+1)*64 + l)*8);
      #pragma unroll
      for (int mf=0; mf<4; mf++){
        bf16x8 A = *reinterpret_cast<const bf16x8*>(lds_h(BufA, pass*64 + mf*16 + lr, ks*32 + lg*8));
        acc[mf][0] = __builtin_amdgcn_mfma_f32_16x16x32_bf16(A, B0, acc[mf][0], 0,0,0);
        acc[mf][1] = __builtin_amdgcn_mfma_f32_16x16x32_bf16(A, B1, acc[mf][1], 0,0,0);
      }
    }
    __syncthreads();   // all reads of this row-half done
    #pragma unroll
    for (int mf=0;mf<4;mf++){
      #pragma unroll
      for (int i=0;i<4;i++){
        int row = pass*64 + mf*16 + lg*4 + i;
        f32x2 x2 = { acc[mf][0][i], acc[mf][1][i] };
        *reinterpret_cast<unsigned int*>(lds_h(BufA, row, c0)) = silu2(x2);
      }
    }
  }

  // ===== layer 2: same structure, W2f + b2 =====
  #pragma unroll
  for (int pass=0; pass<2; ++pass){
    f32x4 acc[4][2];
    #pragma unroll
    for (int mf=0;mf<4;mf++){ acc[mf][0] = (f32x4)0.f; acc[mf][1] = (f32x4)0.f; }
    #pragma unroll
    for (int ks=0; ks<4; ks++){
      bf16x8 B0 = *reinterpret_cast<const bf16x8*>(W2f + ((ks*8 + w*2+0)*64 + l)*8);
      bf16x8 B1 = *reinterpret_cast<const bf16x8*>(W2f + ((ks*8 + w*2+1)*64 + l)*8);
      #pragma unroll
      for (int mf=0; mf<4; mf++){
        bf16x8 A = *reinterpret_cast<const bf16x8*>(lds_h(BufA, pass*64 + mf*16 + lr, ks*32 + lg*8));
        acc[mf][0] = __builtin_amdgcn_mfma_f32_16x16x32_bf16(A, B0, acc[mf][0], 0,0,0);
        acc[mf][1] = __builtin_amdgcn_mfma_f32_16x16x32_bf16(A, B1, acc[mf][1], 0,0,0);
      }
    }
    __syncthreads();
    #pragma unroll
    for (int mf=0;mf<4;mf++){
      #pragma unroll
      for (int i=0;i<4;i++){
        int row = pass*64 + mf*16 + lg*4 + i;
        f32x2 x2 = (f32x2){ acc[mf][0][i], acc[mf][1][i] } + b2p;
        *reinterpret_cast<unsigned int*>(lds_h(BufA, row, c0)) = silu2(x2);
      }
    }
  }
  __syncthreads();     // H2 complete

  // ===== scores = H2 @ W3 (each wave: 2 M-frags) =====
  {
    f32x4 a0 = (f32x4)0.f, a1 = (f32x4)0.f;
    #pragma unroll
    for (int ks=0; ks<4; ks++){
      bf16x8 B3 = *reinterpret_cast<const bf16x8*>(W3f + (ks*64 + l)*8);
      bf16x8 A0 = *reinterpret_cast<const bf16x8*>(lds_h(BufA, (w*2+0)*16 + lr, ks*32 + lg*8));
      bf16x8 A1 = *reinterpret_cast<const bf16x8*>(lds_h(BufA, (w*2+1)*16 + lr, ks*32 + lg*8));
      a0 = __builtin_amdgcn_mfma_f32_16x16x32_bf16(A0, B3, a0, 0,0,0);
      a1 = __builtin_amdgcn_mfma_f32_16x16x32_bf16(A1, B3, a1, 0,0,0);
    }
    #pragma unroll
    for (int i=0;i<4;i++){
      int rin = lg*4 + i;
      if (lr == (rin & 7)){
        sc_l[(w*2+0)*16 + rin] = a0[i] + b3[rin & 7];
        sc_l[(w*2+1)*16 + rin] = a1[i] + b3[rin & 7];
      }
    }
  }
  __syncthreads();

  // ---------- softmax over 16 pairs per head (rows p*8+h) ----------
  if (t < 8){
    const int h = t;
    float m = -1e30f;
    for (int pp=0;pp<16;pp++) m = fmaxf(m, sc_l[pp*8+h]);
    float den = 0.f;
    for (int pp=0;pp<16;pp++){ float wgt = __expf(sc_l[pp*8+h]-m); attn_l[pp*8+h]=wgt; den += wgt; }
    float inv = fast_rcp(den);
    for (int pp=0;pp<16;pp++) attn_l[pp*8+h] *= inv;
  }
  if (t >= 128){
    int idx = t - 128; int pp = idx>>3, h = idx&7;
    gate_l[pp][h] = gate[dstl[pp]*8 + h];
  }
  __syncthreads();

  // ---------- aggregation ----------
  if (t < 128){
    const int h = t >> 4;
    float s = 0.f;
    #pragma unroll
    for (int pp=0;pp<16;pp++) s += attn_l[pp*8+h] * v[dstl[pp]*128 + t];
    feats[t] = s;
  }
  if (t >= 128 && t < 144){
    int pp = t-128;
    float s = 0.f;
    #pragma unroll
    for (int h=0;h<8;h++) s += attn_l[pp*8+h]*gate_l[pp][h];
    cd_l[pp][3] = s;
  }
  __syncthreads();
  if (t < 3){
    float s = 0.f;
    #pragma unroll
    for (int pp=0;pp<16;pp++) s += cd_l[pp][3]*cd_l[pp][t];
    out_c[e*3+t] = coords[e*3+t] + s*0.125f;
  }

  // ---------- y = ef + feats@Wo + bo: K split across both thread-halves ----------
  {
    const int col  = t & 127;
    const int half = t >> 7;
    f32x2 a2 = {0.f, 0.f};
    const float* feats2 = feats + half*64;
    const float* Wocol  = Wo + half*64*128 + col;
    #pragma unroll
    for (int iq=0; iq<32; iq++){
      f32x2 x2 = *reinterpret_cast<const f32x2*>(feats2 + iq*2);
      f32x2 w2 = { Wocol[(iq*2)*128], Wocol[(iq*2+1)*128] };
      a2 += x2 * w2;
    }
    __syncthreads();               // attn_l/sc_l reads all done; safe to overwrite
    wopart[t] = a2.x + a2.y;
  }
  __syncthreads();

  float yv = 0.f;
  if (t < 128){
    yv = ef[e*128+t] + wopart[t] + wopart[t+128] + bo[t];
    float s1 = yv, s2 = yv*yv;
    #pragma unroll
    for (int off=32; off>=1; off>>=1){ s1 += __shfl_xor(s1,off,64); s2 += __shfl_xor(s2,off,64); }
    if ((t&63)==0){ red[(t>>6)*2+0]=s1; red[(t>>6)*2+1]=s2; }
  }
  __syncthreads();
  if (t < 128){
    float sm = red[0]+red[2], sq = red[1]+red[3];
    float mean = sm * (1.f/128.f);
    float var  = sq * (1.f/128.f) - mean*mean;
    float rstd = rsqrtf(var + 1e-5f);
    out_y[e*128+t] = (yv-mean)*rstd*gamma[t] + beta[t];
  }
}

extern "C" void kernel_launch(void* const* d_in, const int* in_sizes, int n_in,
                              void* d_out, int out_size, void* d_ws, size_t ws_size,
                              hipStream_t stream)
{
  const float* ef     = (const float*)d_in[0];
  const float* coords = (const float*)d_in[1];
  const float* Wq  = (const float*)d_in[2];
  const float* Wk  = (const float*)d_in[3];
  const float* Wv  = (const float*)d_in[4];
  const float* W1  = (const float*)d_in[5];
  const float* b1  = (const float*)d_in[6];
  const float* W2  = (const float*)d_in[7];
  const float* b2  = (const float*)d_in[8];
  const float* W3  = (const float*)d_in[9];
  const float* b3  = (const float*)d_in[10];
  const float* Wg1 = (const float*)d_in[11];
  const float* bg1 = (const float*)d_in[12];
  const float* Wg2 = (const float*)d_in[13];
  const float* bg2 = (const float*)d_in[14];
  const float* Wo  = (const float*)d_in[15];
  const float* bo  = (const float*)d_in[16];
  const float* gamma = (const float*)d_in[17];
  const float* beta  = (const float*)d_in[18];
  const int*   pairs = (const int*)d_in[19];

  float* ws   = (float*)d_ws;
  float* q    = ws;
  float* k    = q + E_N*HID;
  float* v    = k + E_N*HID;
  float* gate = v + E_N*HID;
  ushort_t* W1f = (ushort_t*)(gate + E_N*HEADS);
  ushort_t* W2f = W1f + 16384;
  ushort_t* W3f = W2f + 16384;
  ushort_t* Wqf = W3f + 2048;
  ushort_t* Wkf = Wqf + 16384;
  ushort_t* Wvf = Wkf + 16384;

  wprep_kernel<<<328, 256, 0, stream>>>(W1, W2, W3, b1, Wq, Wk, Wv,
      W1f, W2f, W3f, Wqf, Wkf, Wvf);
  qkv_mfma<<<E_N/64, 256, 0, stream>>>(ef, Wqf, Wkf, Wvf, q, k, v);
  gate_kernel<<<E_N, 256, 0, stream>>>(v, Wg1, bg1, Wg2, bg2, gate);
  edge_attn_mfma<<<E_N, 256, 0, stream>>>(ef, coords, q, k, v,
      W1f, W2f, W3f, b2, b3, Wo, bo, gamma, beta, pairs, gate,
      (float*)d_out, (float*)d_out + E_N*HID);
}

// Round 18
// 191.984 us; speedup vs baseline: 1.5094x; 1.0181x over previous
//
#include <hip/hip_runtime.h>
#include <hip/hip_bf16.h>
#include <math.h>

#define E_N   8192
#define K_N   16
#define HID   128
#define HEADS 8
#define HD    16
#define NRAD  64

typedef unsigned short ushort_t;
typedef __attribute__((ext_vector_type(8))) short bf16x8;
typedef __attribute__((ext_vector_type(4))) float f32x4;
typedef __attribute__((ext_vector_type(2))) float f32x2;

__device__ __forceinline__ float fast_rcp(float x){ return __builtin_amdgcn_rcpf(x); }
__device__ __forceinline__ float silu_f(float x){ return x * fast_rcp(1.f + __expf(-x)); }
__device__ __forceinline__ float sigmoid_f(float x){ return fast_rcp(1.f + __expf(-x)); }

__device__ __forceinline__ ushort_t f2b(float x){
  union { __hip_bfloat16 b; ushort_t u; } cv;
  cv.b = __float2bfloat16(x);
  return cv.u;
}
// packed f32x2 -> bf16x2 in one HW instruction (proven R6/R8/R10)
__device__ __forceinline__ unsigned int pk_bf16(float a, float b){
  unsigned int r;
  asm volatile("v_cvt_pk_bf16_f32 %0, %1, %2" : "=v"(r) : "v"(a), "v"(b));
  return r;
}

// silu on a pair -> packed bf16x2 (pure C vector math — R7 lesson: no pk asm)
__device__ __forceinline__ unsigned int silu2(f32x2 x){
  f32x2 t;
  t.x = __expf(-x.x);
  t.y = __expf(-x.y);
  f32x2 d = t + 1.f;
  f32x2 r;
  r.x = fast_rcp(d.x);
  r.y = fast_rcp(d.y);
  f32x2 y = x * r;
  return pk_bf16(y.x, y.y);
}

// swizzled [*][128] bf16 tile: byte = (row*256 + col*2) ^ ((row&7)<<4)
__device__ __forceinline__ void* lds_h(ushort_t* base, int row, int col){
  unsigned int byte = ((unsigned int)(row*256 + col*2)) ^ (((unsigned int)(row & 7)) << 4);
  return (void*)(reinterpret_cast<char*>(base) + byte);
}

// ---------------- Kernel W: pack W1/W2/W3 + Wq/Wk/Wv into MFMA B-frag bf16 --------
// Paired layout (W1,W2): n = (nf>>1)*32 + 2*(l&15) + (nf&1)
// Canonical layout (W3, Wq/Wk/Wv): n = nf*16 + (l&15)
// k = ks*32 + (l>>4)*8 + i for all.  W1: K pad 97->128 with row97 = b1.  W3: N pad 8->16.
__global__ __launch_bounds__(256) void wprep_kernel(
    const float* __restrict__ W1, const float* __restrict__ W2, const float* __restrict__ W3,
    const float* __restrict__ b1,
    const float* __restrict__ Wq, const float* __restrict__ Wk, const float* __restrict__ Wv,
    ushort_t* __restrict__ W1f, ushort_t* __restrict__ W2f, ushort_t* __restrict__ W3f,
    ushort_t* __restrict__ Wqf, ushort_t* __restrict__ Wkf, ushort_t* __restrict__ Wvf)
{
  int idx = blockIdx.x*256 + threadIdx.x;    // 0..83967
  if (idx < 32768){
    int id  = idx & 16383;
    int i  = id & 7;
    int l  = (id >> 3) & 63;
    int nf = (id >> 9) & 7;
    int ks = (id >> 12) & 3;
    int kk = ks*32 + (l>>4)*8 + i;
    int n  = (nf>>1)*32 + 2*(l&15) + (nf&1);
    if (idx < 16384){
      float val = (kk < 97) ? W1[kk*128 + n] : (kk == 97 ? b1[n] : 0.f);
      W1f[id] = f2b(val);
    } else {
      W2f[id] = f2b(W2[kk*128 + n]);
    }
  } else if (idx < 34816){
    int id = idx - 32768;                    // 0..2047
    int i  = id & 7;
    int l  = (id >> 3) & 63;
    int ks = (id >> 9) & 3;
    int kk = ks*32 + (l>>4)*8 + i;
    int n  = l & 15;
    W3f[id] = (n < 8) ? f2b(W3[kk*8 + n]) : (ushort_t)0;
  } else if (idx < 83968){
    int id = idx - 34816;                    // 0..49151
    int m  = id >> 14;                       // 0:q 1:k 2:v
    int r  = id & 16383;
    int i  = r & 7;
    int l  = (r >> 3) & 63;
    int nf = (r >> 9) & 7;
    int ks = (r >> 12) & 3;
    int kk = ks*32 + (l>>4)*8 + i;
    int n  = nf*16 + (l&15);
    const float* Wm = (m==0) ? Wq : ((m==1) ? Wk : Wv);
    ushort_t*    Dm = (m==0) ? Wqf : ((m==1) ? Wkf : Wvf);
    Dm[r] = f2b(Wm[kk*128 + n]);
  }
}

// ---------------- Kernel A: q,k,v = ef @ {Wq,Wk,Wv} via bf16 MFMA -----------------
// 32 rows per block (256 blocks -> full CU coverage).  Wave w owns cols [32w,32w+32).
__global__ __launch_bounds__(256) void qkv_mfma(
    const float* __restrict__ ef,
    const ushort_t* __restrict__ Wqf, const ushort_t* __restrict__ Wkf,
    const ushort_t* __restrict__ Wvf,
    float* __restrict__ q, float* __restrict__ k, float* __restrict__ v)
{
  __shared__ __align__(16) ushort_t EfT[32*128];   // swizzled bf16 tile
  const int t = threadIdx.x;
  const int w  = t >> 6;
  const int l  = t & 63;
  const int lr = l & 15;
  const int lg = l >> 4;
  const int base = blockIdx.x * 32;

  {
    int r = t >> 3, qr = t & 7;                    // 1/8 row each: 16 cols
    const float4* src = reinterpret_cast<const float4*>(ef + (base + r)*128 + qr*16);
    #pragma unroll
    for (int i4=0;i4<4;i4++){
      float4 xv = src[i4];
      *reinterpret_cast<unsigned int*>(lds_h(EfT, r, qr*16 + i4*4    )) = pk_bf16(xv.x, xv.y);
      *reinterpret_cast<unsigned int*>(lds_h(EfT, r, qr*16 + i4*4 + 2)) = pk_bf16(xv.z, xv.w);
    }
  }
  __syncthreads();

  bf16x8 Afr[2][4];
  #pragma unroll
  for (int mf=0;mf<2;mf++)
    #pragma unroll
    for (int ks=0;ks<4;ks++)
      Afr[mf][ks] = *reinterpret_cast<const bf16x8*>(lds_h(EfT, mf*16 + lr, ks*32 + lg*8));

  #pragma unroll
  for (int m=0;m<3;m++){
    const ushort_t* Wf = (m==0) ? Wqf : ((m==1) ? Wkf : Wvf);
    float*          Om = (m==0) ? q   : ((m==1) ? k   : v);
    f32x4 acc[2][2];
    #pragma unroll
    for (int mf=0;mf<2;mf++){ acc[mf][0] = (f32x4)0.f; acc[mf][1] = (f32x4)0.f; }
    #pragma unroll
    for (int ks=0; ks<4; ks++){
      bf16x8 B0 = *reinterpret_cast<const bf16x8*>(Wf + ((ks*8 + w*2+0)*64 + l)*8);
      bf16x8 B1 = *reinterpret_cast<const bf16x8*>(Wf + ((ks*8 + w*2+1)*64 + l)*8);
      #pragma unroll
      for (int mf=0; mf<2; mf++){
        acc[mf][0] = __builtin_amdgcn_mfma_f32_16x16x32_bf16(Afr[mf][ks], B0, acc[mf][0], 0,0,0);
        acc[mf][1] = __builtin_amdgcn_mfma_f32_16x16x32_bf16(Afr[mf][ks], B1, acc[mf][1], 0,0,0);
      }
    }
    #pragma unroll
    for (int mf=0;mf<2;mf++)
      #pragma unroll
      for (int nf=0;nf<2;nf++)
        #pragma unroll
        for (int i=0;i<4;i++){
          int row = base + mf*16 + lg*4 + i;
          int col = w*32 + nf*16 + lr;
          Om[row*128 + col] = acc[mf][nf][i];
        }
  }
}

// ---------------- Kernel B: gate[e][h] ----------------
__global__ __launch_bounds__(256) void gate_kernel(
    const float* __restrict__ v,
    const float* __restrict__ Wg1, const float* __restrict__ bg1,
    const float* __restrict__ Wg2, const float* __restrict__ bg2,
    float* __restrict__ gate)
{
  const int e = blockIdx.x;
  const int t = threadIdx.x;
  const int h = t >> 5, l = t & 31;
  float vp[16];
  #pragma unroll
  for (int i=0;i<16;i++) vp[i] = v[e*128 + h*16 + i];
  float part = 0.f;
  #pragma unroll
  for (int jj=0;jj<4;jj++){
    int j = l + jj*32;
    float a = bg1[j];
    #pragma unroll
    for (int i=0;i<16;i++) a += vp[i]*Wg1[i*128+j];
    part += silu_f(a) * Wg2[j];
  }
  #pragma unroll
  for (int off=16; off>=1; off>>=1) part += __shfl_xor(part, off, 64);
  if (l==0) gate[e*8+h] = sigmoid_f(part + bg2[0]);
}

// ---------------- Kernel C: MFMA fused edge attention (R8/R10 structure) -----------
// N-split: wave w owns output cols [32w, 32w+32).  Two M-passes per layer with
// acc[4][2] (32 AGPR).  X/H1/H2 time-share ONE 32 KB swizzled LDS tile.
__global__ __launch_bounds__(256) void edge_attn_mfma(
    const float* __restrict__ ef, const float* __restrict__ coords,
    const float* __restrict__ q, const float* __restrict__ k, const float* __restrict__ v,
    const ushort_t* __restrict__ W1f, const ushort_t* __restrict__ W2f,
    const ushort_t* __restrict__ W3f,
    const float* __restrict__ b2, const float* __restrict__ b3,
    const float* __restrict__ Wo, const float* __restrict__ bo,
    const float* __restrict__ gamma, const float* __restrict__ beta,
    const int* __restrict__ pairs, const float* __restrict__ gate,
    float* __restrict__ out_y, float* __restrict__ out_c)
{
  __shared__ __align__(16) ushort_t BufA[128*128];   // X -> H1 -> H2 (swizzled)
  __shared__ __align__(16) float SmallBuf[416];      // sc[128], attn[128], feats[128], red[4]
  __shared__ float cd_l[16][4];
  __shared__ float gate_l[16][8];
  __shared__ int   dstl[16];

  float* sc_l   = SmallBuf;          // reused as wopart[256] in epilogue
  float* attn_l = SmallBuf + 128;
  float* feats  = SmallBuf + 256;
  float* red    = SmallBuf + 384;
  float* wopart = SmallBuf;

  const int e = blockIdx.x;
  const int t = threadIdx.x;
  const int w  = t >> 6;
  const int l  = t & 63;
  const int lr = l & 15;        // A-row / B-col / C-col within fragment
  const int lg = l >> 4;        // k-group / C-row-group (= pair group in setup)

  // ---------- per-lane setup: pair, coord diff, rb (all wave-local) ----------
  const int pg   = lg;                 // 0..3, this lane-group's pair within the wave
  const int p    = w*4 + pg;
  const int dstp = pairs[(e*16 + p)*2 + 1];
  if (l < 4) dstl[w*4 + l] = pairs[(e*16 + w*4 + l)*2 + 1];

  float cx = coords[e*3+0]-coords[dstp*3+0];
  float cy = coords[e*3+1]-coords[dstp*3+1];
  float cz = coords[e*3+2]-coords[dstp*3+2];
  float dist = sqrtf(cx*cx+cy*cy+cz*cz);
  if (lr < 3) cd_l[p][lr] = (lr==0) ? cx : (lr==1 ? cy : cz);

  // rb: each lane computes 4 centers, writes them (packed) to all 8 rows of its pair
  {
    int i0 = lr * 4;
    float z0 = (dist - (float)(i0+0)*(10.0f/63.0f)) * 6.4f;
    float z1 = (dist - (float)(i0+1)*(10.0f/63.0f)) * 6.4f;
    float z2 = (dist - (float)(i0+2)*(10.0f/63.0f)) * 6.4f;
    float z3 = (dist - (float)(i0+3)*(10.0f/63.0f)) * 6.4f;
    unsigned int u01 = pk_bf16(__expf(-z0*z0), __expf(-z1*z1));
    unsigned int u23 = pk_bf16(__expf(-z2*z2), __expf(-z3*z3));
    int base_row = w*32 + pg*8;
    #pragma unroll
    for (int rr=0; rr<8; rr++){
      *reinterpret_cast<unsigned int*>(lds_h(BufA, base_row+rr, 32+i0  )) = u01;
      *reinterpret_cast<unsigned int*>(lds_h(BufA, base_row+rr, 32+i0+2)) = u23;
    }
  }

  // q/k/dot/bias-1/zeros: 2 lanes per row (wave-local rows [32w, 32w+32))
  {
    const int rl  = l >> 1;
    const int hf  = l & 1;
    const int row = w*32 + rl;
    const int hh  = rl & 7;
    float dot = 0.f;
    if (hf == 0){
      const float4* qp4 = reinterpret_cast<const float4*>(q + e*128 + hh*16);
      const float4* kp4 = reinterpret_cast<const float4*>(k + dstp*128 + hh*16);
      #pragma unroll
      for (int i4=0;i4<4;i4++){
        float4 qv = qp4[i4], kv = kp4[i4];
        dot += qv.x*kv.x + qv.y*kv.y + qv.z*kv.z + qv.w*kv.w;
        *reinterpret_cast<unsigned int*>(lds_h(BufA, row, i4*4     )) = pk_bf16(qv.x, qv.y);
        *reinterpret_cast<unsigned int*>(lds_h(BufA, row, i4*4+2   )) = pk_bf16(qv.z, qv.w);
        *reinterpret_cast<unsigned int*>(lds_h(BufA, row, 16+i4*4  )) = pk_bf16(kv.x, kv.y);
        *reinterpret_cast<unsigned int*>(lds_h(BufA, row, 16+i4*4+2)) = pk_bf16(kv.z, kv.w);
      }
    }
    float dsw = __shfl_xor(dot, 1, 64);
    if (hf == 1){
      *reinterpret_cast<unsigned int*>(lds_h(BufA, row, 96)) = pk_bf16(dsw, 1.0f);
      #pragma unroll
      for (int c=98;c<128;c+=2)
        *reinterpret_cast<unsigned int*>(lds_h(BufA, row, c)) = 0u;
    }
  }
  __syncthreads();     // X complete

  const int c0 = w*32 + 2*lr;               // this wave's packed output col pair
  const f32x2 b2p = { b2[c0], b2[c0+1] };   // layer-2 bias (layer-1 bias folded)

  // ===== layer 1: two M-passes, acc[4][2] =====
  #pragma unroll
  for (int pass=0; pass<2; ++pass){
    f32x4 acc[4][2];
    #pragma unroll
    for (int mf=0;mf<4;mf++){ acc[mf][0] = (f32x4)0.f; acc[mf][1] = (f32x4)0.f; }
    #pragma unroll
    for (int ks=0; ks<4; ks++){
      bf16x8 B0 = *reinterpret_cast<const bf16x8*>(W1f + ((ks*8 + w*2+0)*64 + l)*8);
      bf16x8 B1 = *reinterpret_cast<const bf16x8*>(W1f + ((ks*8 + w*2+1)*64 + l)*8);
      #pragma unroll
      for (int mf=0; mf<4; mf++){
        bf16x8 A = *reinterpret_cast<const bf16x8*>(lds_h(BufA, pass*64 + mf*16 + lr, ks*32 + lg*8));
        acc[mf][0] = __builtin_amdgcn_mfma_f32_16x16x32_bf16(A, B0, acc[mf][0], 0,0,0);
        acc[mf][1] = __builtin_amdgcn_mfma_f32_16x16x32_bf16(A, B1, acc[mf][1], 0,0,0);
      }
    }
    __syncthreads();   // all reads of this row-half done
    #pragma unroll
    for (int mf=0;mf<4;mf++){
      #pragma unroll
      for (int i=0;i<4;i++){
        int row = pass*64 + mf*16 + lg*4 + i;
        f32x2 x2 = { acc[mf][0][i], acc[mf][1][i] };
        *reinterpret_cast<unsigned int*>(lds_h(BufA, row, c0)) = silu2(x2);
      }
    }
  }

  // ===== layer 2: same structure, W2f + b2 =====
  #pragma unroll
  for (int pass=0; pass<2; ++pass){
    f32x4 acc[4][2];
    #pragma unroll
    for (int mf=0;mf<4;mf++){ acc[mf][0] = (f32x4)0.f; acc[mf][1] = (f32x4)0.f; }
    #pragma unroll
    for (int ks=0; ks<4; ks++){
      bf16x8 B0 = *reinterpret_cast<const bf16x8*>(W2f + ((ks*8 + w*2+0)*64 + l)*8);
      bf16x8 B1 = *reinterpret_cast<const bf16x8*>(W2f + ((ks*8 + w*2+1)*64 + l)*8);
      #pragma unroll
      for (int mf=0; mf<4; mf++){
        bf16x8 A = *reinterpret_cast<const bf16x8*>(lds_h(BufA, pass*64 + mf*16 + lr, ks*32 + lg*8));
        acc[mf][0] = __builtin_amdgcn_mfma_f32_16x16x32_bf16(A, B0, acc[mf][0], 0,0,0);
        acc[mf][1] = __builtin_amdgcn_mfma_f32_16x16x32_bf16(A, B1, acc[mf][1], 0,0,0);
      }
    }
    __syncthreads();
    #pragma unroll
    for (int mf=0;mf<4;mf++){
      #pragma unroll
      for (int i=0;i<4;i++){
        int row = pass*64 + mf*16 + lg*4 + i;
        f32x2 x2 = (f32x2){ acc[mf][0][i], acc[mf][1][i] } + b2p;
        *reinterpret_cast<unsigned int*>(lds_h(BufA, row, c0)) = silu2(x2);
      }
    }
  }
  __syncthreads();     // H2 complete

  // ===== scores = H2 @ W3 (each wave: 2 M-frags) =====
  {
    f32x4 a0 = (f32x4)0.f, a1 = (f32x4)0.f;
    #pragma unroll
    for (int ks=0; ks<4; ks++){
      bf16x8 B3 = *reinterpret_cast<const bf16x8*>(W3f + (ks*64 + l)*8);
      bf16x8 A0 = *reinterpret_cast<const bf16x8*>(lds_h(BufA, (w*2+0)*16 + lr, ks*32 + lg*8));
      bf16x8 A1 = *reinterpret_cast<const bf16x8*>(lds_h(BufA, (w*2+1)*16 + lr, ks*32 + lg*8));
      a0 = __builtin_amdgcn_mfma_f32_16x16x32_bf16(A0, B3, a0, 0,0,0);
      a1 = __builtin_amdgcn_mfma_f32_16x16x32_bf16(A1, B3, a1, 0,0,0);
    }
    #pragma unroll
    for (int i=0;i<4;i++){
      int rin = lg*4 + i;
      if (lr == (rin & 7)){
        sc_l[(w*2+0)*16 + rin] = a0[i] + b3[rin & 7];
        sc_l[(w*2+1)*16 + rin] = a1[i] + b3[rin & 7];
      }
    }
  }
  __syncthreads();

  // ---------- softmax over 16 pairs per head (rows p*8+h) ----------
  if (t < 8){
    const int h = t;
    float m = -1e30f;
    for (int pp=0;pp<16;pp++) m = fmaxf(m, sc_l[pp*8+h]);
    float den = 0.f;
    for (int pp=0;pp<16;pp++){ float wgt = __expf(sc_l[pp*8+h]-m); attn_l[pp*8+h]=wgt; den += wgt; }
    float inv = fast_rcp(den);
    for (int pp=0;pp<16;pp++) attn_l[pp*8+h] *= inv;
  }
  if (t >= 128){
    int idx = t - 128; int pp = idx>>3, h = idx&7;
    gate_l[pp][h] = gate[dstl[pp]*8 + h];
  }
  __syncthreads();

  // ---------- aggregation ----------
  if (t < 128){
    const int h = t >> 4;
    float s = 0.f;
    #pragma unroll
    for (int pp=0;pp<16;pp++) s += attn_l[pp*8+h] * v[dstl[pp]*128 + t];
    feats[t] = s;
  }
  if (t >= 128 && t < 144){
    int pp = t-128;
    float s = 0.f;
    #pragma unroll
    for (int h=0;h<8;h++) s += attn_l[pp*8+h]*gate_l[pp][h];
    cd_l[pp][3] = s;
  }
  __syncthreads();
  if (t < 3){
    float s = 0.f;
    #pragma unroll
    for (int pp=0;pp<16;pp++) s += cd_l[pp][3]*cd_l[pp][t];
    out_c[e*3+t] = coords[e*3+t] + s*0.125f;
  }

  // ---------- y = ef + feats@Wo + bo: K split across both thread-halves ----------
  {
    const int col  = t & 127;
    const int half = t >> 7;
    f32x2 a2 = {0.f, 0.f};
    const float* feats2 = feats + half*64;
    const float* Wocol  = Wo + half*64*128 + col;
    #pragma unroll
    for (int iq=0; iq<32; iq++){
      f32x2 x2 = *reinterpret_cast<const f32x2*>(feats2 + iq*2);
      f32x2 w2 = { Wocol[(iq*2)*128], Wocol[(iq*2+1)*128] };
      a2 += x2 * w2;
    }
    __syncthreads();               // attn_l/sc_l reads all done; safe to overwrite
    wopart[t] = a2.x + a2.y;
  }
  __syncthreads();

  float yv = 0.f;
  if (t < 128){
    yv = ef[e*128+t] + wopart[t] + wopart[t+128] + bo[t];
    float s1 = yv, s2 = yv*yv;
    #pragma unroll
    for (int off=32; off>=1; off>>=1){ s1 += __shfl_xor(s1,off,64); s2 += __shfl_xor(s2,off,64); }
    if ((t&63)==0){ red[(t>>6)*2+0]=s1; red[(t>>6)*2+1]=s2; }
  }
  __syncthreads();
  if (t < 128){
    float sm = red[0]+red[2], sq = red[1]+red[3];
    float mean = sm * (1.f/128.f);
    float var  = sq * (1.f/128.f) - mean*mean;
    float rstd = rsqrtf(var + 1e-5f);
    out_y[e*128+t] = (yv-mean)*rstd*gamma[t] + beta[t];
  }
}

extern "C" void kernel_launch(void* const* d_in, const int* in_sizes, int n_in,
                              void* d_out, int out_size, void* d_ws, size_t ws_size,
                              hipStream_t stream)
{
  const float* ef     = (const float*)d_in[0];
  const float* coords = (const float*)d_in[1];
  const float* Wq  = (const float*)d_in[2];
  const float* Wk  = (const float*)d_in[3];
  const float* Wv  = (const float*)d_in[4];
  const float* W1  = (const float*)d_in[5];
  const float* b1  = (const float*)d_in[6];
  const float* W2  = (const float*)d_in[7];
  const float* b2  = (const float*)d_in[8];
  const float* W3  = (const float*)d_in[9];
  const float* b3  = (const float*)d_in[10];
  const float* Wg1 = (const float*)d_in[11];
  const float* bg1 = (const float*)d_in[12];
  const float* Wg2 = (const float*)d_in[13];
  const float* bg2 = (const float*)d_in[14];
  const float* Wo  = (const float*)d_in[15];
  const float* bo  = (const float*)d_in[16];
  const float* gamma = (const float*)d_in[17];
  const float* beta  = (const float*)d_in[18];
  const int*   pairs = (const int*)d_in[19];

  float* ws   = (float*)d_ws;
  float* q    = ws;
  float* k    = q + E_N*HID;
  float* v    = k + E_N*HID;
  float* gate = v + E_N*HID;
  ushort_t* W1f = (ushort_t*)(gate + E_N*HEADS);
  ushort_t* W2f = W1f + 16384;
  ushort_t* W3f = W2f + 16384;
  ushort_t* Wqf = W3f + 2048;
  ushort_t* Wkf = Wqf + 16384;
  ushort_t* Wvf = Wkf + 16384;

  wprep_kernel<<<328, 256, 0, stream>>>(W1, W2, W3, b1, Wq, Wk, Wv,
      W1f, W2f, W3f, Wqf, Wkf, Wvf);
  qkv_mfma<<<E_N/32, 256, 0, stream>>>(ef, Wqf, Wkf, Wvf, q, k, v);
  gate_kernel<<<E_N, 256, 0, stream>>>(v, Wg1, bg1, Wg2, bg2, gate);
  edge_attn_mfma<<<E_N, 256, 0, stream>>>(ef, coords, q, k, v,
      W1f, W2f, W3f, b2, b3, Wo, bo, gamma, beta, pairs, gate,
      (float*)d_out, (float*)d_out + E_N*HID);
}